// Round 7
// baseline (266.500 us; speedup 1.0000x reference)
//
#include <hip/hip_runtime.h>

// B=32, T=512, D=64, V=60
// inputs: [0] input_ids int32 [32*512], [1] repr_tab f32 [60*64*64],
//         [2] W1 f32 [4096*64], [3] b1 f32 [64], [4] W2 f32 [64*60], [5] b2 f32 [60]
// output: logits f32 [32*60]
//
// Pipeline:
//   qr_kernel    (60 blocks):  ROUND-4-VALIDATED Householder QR (LAPACK convention),
//                              one wave, shfl-broadcast column, masked normalized v,
//                              forward-fused Q accumulation. ONLY change vs round 4:
//                              __launch_bounds__(64, 1) -> no VGPR cap, no spills.
//   scan1_kernel (512 blocks): chains of 32 Q-factors; S in LDS (bf16 hi/lo, B-layout);
//                              A-fragments direct global->reg, prefetched; 3-term
//                              split-bf16 MFMA (32x32x16) via compiler builtin.
//   scan2_kernel (32 blocks):  product of 16 chunk-products per batch + fused readout.
//
// Layout glossary (all bf16 planes are 4096 shorts; hi plane at +0, lo at +4096):
//   granule(row r, G=k>>3) at short offset r*64 + ((G ^ (r&7) ^ (r>>3)) << 3) + (k&7)
//   A-plane: r indexes the MFMA A operand rows, k its K-dim (8 consecutive)
//   B-plane: r indexes the MFMA B operand cols, k its K-dim (8 consecutive)
//   Empirically validated mapping (rounds 2/4): forward-fused q -> A-plane direct;
//   LDS-transposed q -> B-plane.

typedef short v8s __attribute__((ext_vector_type(8)));
typedef short v4s __attribute__((ext_vector_type(4)));
typedef float v16f __attribute__((ext_vector_type(16)));
typedef __bf16 bf16x8 __attribute__((ext_vector_type(8)));

// f32 -> (hi, lo) bf16 with RNE, branch-free bit tricks.
__device__ __forceinline__ void split_one(float f, unsigned& hi, unsigned& lo) {
    unsigned u = __float_as_uint(f);
    unsigned rh = u + 0x7fffu + ((u >> 16) & 1u);
    float fh = __uint_as_float(rh & 0xffff0000u);
    hi = rh >> 16;
    float g = f - fh;                     // exact (Sterbenz)
    unsigned ul = __float_as_uint(g);
    unsigned rl = ul + 0x7fffu + ((ul >> 16) & 1u);
    lo = rl >> 16;
}

__device__ __forceinline__ void split4(const float* f, v4s& hi4, v4s& lo4) {
#pragma unroll
    for (int r = 0; r < 4; ++r) {
        unsigned h, l;
        split_one(f[r], h, l);
        hi4[r] = (short)h;
        lo4[r] = (short)l;
    }
}

__device__ __forceinline__ void split8(const float* f, v8s& hi8, v8s& lo8) {
#pragma unroll
    for (int r = 0; r < 8; ++r) {
        unsigned h, l;
        split_one(f[r], h, l);
        hi8[r] = (short)h;
        lo8[r] = (short)l;
    }
}

// ---------------- Kernel 1: barrier-free one-wave Householder QR ----------------
// ROUND-4 math, verbatim. Lane l holds column l of A and accumulator q.
// LAPACK sgeqr2 convention: beta = -sign(alpha)*norm, tau=(beta-alpha)/beta,
// v_i = x_i/(alpha-beta), v_k=1. Q accumulated forward: q <- q - tau*(q.v)*v.
__global__ __launch_bounds__(64, 1) void qr_kernel(const float* __restrict__ repr,
                                                   unsigned short* __restrict__ qtabA,
                                                   unsigned short* __restrict__ qtabB) {
    const int l = threadIdx.x;
    const int v = blockIdx.x;
    const float* src = repr + v * 4096;

    float a[64];   // column l of A
    float q[64];   // forward-fused Q accumulator
#pragma unroll
    for (int i = 0; i < 64; ++i) a[i] = src[i * 64 + l];
#pragma unroll
    for (int i = 0; i < 64; ++i) q[i] = (i == l) ? 1.f : 0.f;

#pragma unroll 1
    for (int k = 0; k < 64; ++k) {
        float vr[64];
#pragma unroll
        for (int i = 0; i < 64; ++i) vr[i] = __shfl(a[i], k);

        float s0 = 0.f, s1 = 0.f, s2 = 0.f, s3 = 0.f;
#pragma unroll
        for (int i = 0; i < 64; i += 4) {
            s0 += (i     > k) ? vr[i]     * vr[i]     : 0.f;
            s1 += (i + 1 > k) ? vr[i + 1] * vr[i + 1] : 0.f;
            s2 += (i + 2 > k) ? vr[i + 2] * vr[i + 2] : 0.f;
            s3 += (i + 3 > k) ? vr[i + 3] * vr[i + 3] : 0.f;
        }
        float sigma = (s0 + s1) + (s2 + s3);
        float al = 0.f;
#pragma unroll
        for (int i = 0; i < 64; ++i) al = (i == k) ? vr[i] : al;

        float beta, tau, scl;
        if (sigma == 0.f) { beta = al; tau = 0.f; scl = 0.f; }
        else {
            beta = -copysignf(sqrtf(al * al + sigma), al);
            tau = (beta - al) / beta;
            scl = 1.f / (al - beta);
        }

#pragma unroll
        for (int i = 0; i < 64; ++i) vr[i] = (i < k) ? 0.f : ((i == k) ? 1.f : vr[i] * scl);

        float w0 = 0.f, w1 = 0.f, w2 = 0.f, w3 = 0.f;
#pragma unroll
        for (int i = 0; i < 64; i += 4) {
            w0 += vr[i] * a[i]; w1 += vr[i + 1] * a[i + 1];
            w2 += vr[i + 2] * a[i + 2]; w3 += vr[i + 3] * a[i + 3];
        }
        float tw = tau * ((w0 + w1) + (w2 + w3));
#pragma unroll
        for (int i = 0; i < 64; ++i) a[i] -= tw * vr[i];

        float u0 = 0.f, u1 = 0.f, u2 = 0.f, u3 = 0.f;
#pragma unroll
        for (int j = 0; j < 64; j += 4) {
            u0 += q[j] * vr[j]; u1 += q[j + 1] * vr[j + 1];
            u2 += q[j + 2] * vr[j + 2]; u3 += q[j + 3] * vr[j + 3];
        }
        float tu = tau * ((u0 + u1) + (u2 + u3));
#pragma unroll
        for (int j = 0; j < 64; ++j) q[j] -= tu * vr[j];
    }

    // ---- A-plane DIRECT from q (round-2/4 validated mapping) ----
    {
        unsigned short* dstA = qtabA + (size_t)v * 8192 + (size_t)l * 64;
#pragma unroll
        for (int G = 0; G < 8; ++G) {
            v8s hi8, lo8;
            split8(&q[8 * G], hi8, lo8);
            const int sl = (G ^ (l & 7) ^ (l >> 3)) << 3;
            *reinterpret_cast<v8s*>(&dstA[sl]) = hi8;
            *reinterpret_cast<v8s*>(&dstA[4096 + sl]) = lo8;
        }
    }
    // ---- transpose through LDS, then B-plane (round-2/4 validated mapping) ----
    __shared__ float tr[64 * 65];
#pragma unroll
    for (int j = 0; j < 64; ++j) tr[l * 65 + j] = q[j];
    __syncthreads();
    {
        unsigned short* dstB = qtabB + (size_t)v * 8192 + (size_t)l * 64;
#pragma unroll
        for (int G = 0; G < 8; ++G) {
            float cv[8];
#pragma unroll
            for (int i = 0; i < 8; ++i) cv[i] = tr[(8 * G + i) * 65 + l];
            v8s hi8, lo8;
            split8(cv, hi8, lo8);
            const int sl = (G ^ (l & 7) ^ (l >> 3)) << 3;
            *reinterpret_cast<v8s*>(&dstB[sl]) = hi8;
            *reinterpret_cast<v8s*>(&dstB[4096 + sl]) = lo8;
        }
    }
}

// ---------------- Kernel 2: chains of 32 factors, 4 waves, MFMA ----------------
__global__ __launch_bounds__(256) void scan1_kernel(const int* __restrict__ ids,
                                                    const unsigned short* __restrict__ qtabA,
                                                    const unsigned short* __restrict__ qtabB,
                                                    unsigned short* __restrict__ PA,
                                                    unsigned short* __restrict__ PB) {
    __shared__ unsigned short SBm[8192];   // hi plane [0,4096), lo plane [4096,8192)
    __shared__ int ids_s[32];
    const int t = threadIdx.x;
    const int l = t & 63, w = t >> 6;
    const int rw = w >> 1, cw = w & 1, h = l >> 5;
    const int b = blockIdx.x >> 4, c = blockIdx.x & 15;
    if (t < 32) ids_s[t] = ids[b * 512 + c * 32 + t];

    const int m = 32 * rw + (l & 31);   // A-operand row
    const int n = 32 * cw + (l & 31);   // B-operand / D col
    int aoff[8], boff[4], doff[4];
#pragma unroll
    for (int s4 = 0; s4 < 4; ++s4) {
        const int G = 2 * s4 + h;
        aoff[s4]     = m * 64 + ((G ^ (m & 7) ^ (m >> 3)) << 3);
        aoff[s4 + 4] = aoff[s4] + 4096;
        boff[s4]     = n * 64 + ((G ^ (n & 7) ^ (n >> 3)) << 3);
    }
#pragma unroll
    for (int rg = 0; rg < 4; ++rg)
        doff[rg] = n * 64 + (((4 * rw + rg) ^ (n & 7) ^ (n >> 3)) << 3) + 4 * h;

    __syncthreads();   // ids_s visible

    // stage S = Q[ids[0]] (B-layout, linear copy)
    {
        const unsigned short* srcB = qtabB + (size_t)ids_s[0] * 8192;
#pragma unroll
        for (int u = 0; u < 4; ++u)
            *reinterpret_cast<v8s*>(&SBm[t * 32 + u * 8]) =
                *reinterpret_cast<const v8s*>(&srcB[t * 32 + u * 8]);
    }
    // prefetch A-fragments for factor 1
    bf16x8 cur[8], nxt[8];
    {
        const unsigned short* ga = qtabA + (size_t)ids_s[1] * 8192;
#pragma unroll
        for (int qv = 0; qv < 8; ++qv)
            cur[qv] = *reinterpret_cast<const bf16x8*>(&ga[aoff[qv]]);
    }
    __syncthreads();   // SBm staged

#pragma unroll 1
    for (int j = 1; j < 32; ++j) {
        const int vn = ids_s[(j < 31) ? (j + 1) : 31];
        const unsigned short* ga = qtabA + (size_t)vn * 8192;
#pragma unroll
        for (int qv = 0; qv < 8; ++qv)
            nxt[qv] = *reinterpret_cast<const bf16x8*>(&ga[aoff[qv]]);

        v16f acc;
#pragma unroll
        for (int z = 0; z < 16; ++z) acc[z] = 0.f;

#pragma unroll
        for (int s4 = 0; s4 < 4; ++s4) {
            bf16x8 bh = *reinterpret_cast<const bf16x8*>(&SBm[boff[s4]]);
            bf16x8 bl = *reinterpret_cast<const bf16x8*>(&SBm[4096 + boff[s4]]);
            acc = __builtin_amdgcn_mfma_f32_32x32x16_bf16(cur[s4 + 4], bh, acc, 0, 0, 0); // lo*hi
            acc = __builtin_amdgcn_mfma_f32_32x32x16_bf16(cur[s4], bl, acc, 0, 0, 0);     // hi*lo
            acc = __builtin_amdgcn_mfma_f32_32x32x16_bf16(cur[s4], bh, acc, 0, 0, 0);     // hi*hi
        }
        __syncthreads();   // all B-reads done before S is overwritten
#pragma unroll
        for (int rg = 0; rg < 4; ++rg) {
            float f[4];
#pragma unroll
            for (int r = 0; r < 4; ++r) f[r] = acc[4 * rg + r];
            v4s hi4, lo4;
            split4(f, hi4, lo4);
            *reinterpret_cast<v4s*>(&SBm[doff[rg]]) = hi4;
            *reinterpret_cast<v4s*>(&SBm[4096 + doff[rg]]) = lo4;
        }
        __syncthreads();   // new S visible
#pragma unroll
        for (int qv = 0; qv < 8; ++qv) cur[qv] = nxt[qv];
    }

    if (c == 0) {
        // B-layout copy (linear) for scan2's initial state
        unsigned short* dst = PB + (size_t)b * 8192;
#pragma unroll
        for (int u = 0; u < 4; ++u)
            *reinterpret_cast<v8s*>(&dst[t * 32 + u * 8]) =
                *reinterpret_cast<const v8s*>(&SBm[t * 32 + u * 8]);
    } else {
        // gather-transpose SBm (B-layout) -> A-layout global
        unsigned short* dst = PA + (size_t)(b * 16 + c) * 8192;
        const int mm = t & 63;
#pragma unroll
        for (int u = 0; u < 4; ++u) {
            const int p = u & 1;
            const int G = 2 * (t >> 6) + (u >> 1);
            v8s pk;
#pragma unroll
            for (int i = 0; i < 8; ++i)
                pk[i] = (short)SBm[p * 4096 + (8 * G + i) * 64 +
                                   (((mm >> 3) ^ i ^ G) << 3) + (mm & 7)];
            *reinterpret_cast<v8s*>(
                &dst[p * 4096 + mm * 64 + ((G ^ (mm & 7) ^ (mm >> 3)) << 3)]) = pk;
        }
    }
}

// ---------------- Kernel 3: per-batch product of 16 chunks + readout ----------------
__global__ __launch_bounds__(256) void scan2_kernel(const unsigned short* __restrict__ PA,
                                                    const unsigned short* __restrict__ PB,
                                                    const float* __restrict__ W1,
                                                    const float* __restrict__ b1,
                                                    const float* __restrict__ W2,
                                                    const float* __restrict__ b2,
                                                    float* __restrict__ out) {
    __shared__ unsigned short SBm[8192];
    __shared__ float Sf[64 * 68];
    __shared__ float hl[64];
    const int t = threadIdx.x;
    const int l = t & 63, w = t >> 6;
    const int rw = w >> 1, cw = w & 1, h = l >> 5;
    const int b = blockIdx.x;

    const int m = 32 * rw + (l & 31);
    const int n = 32 * cw + (l & 31);
    int aoff[8], boff[4], doff[4];
#pragma unroll
    for (int s4 = 0; s4 < 4; ++s4) {
        const int G = 2 * s4 + h;
        aoff[s4]     = m * 64 + ((G ^ (m & 7) ^ (m >> 3)) << 3);
        aoff[s4 + 4] = aoff[s4] + 4096;
        boff[s4]     = n * 64 + ((G ^ (n & 7) ^ (n >> 3)) << 3);
    }
#pragma unroll
    for (int rg = 0; rg < 4; ++rg)
        doff[rg] = n * 64 + (((4 * rw + rg) ^ (n & 7) ^ (n >> 3)) << 3) + 4 * h;

    // stage S = chunk(b*16 + 0) from PB
    {
        const unsigned short* srcB = PB + (size_t)b * 8192;
#pragma unroll
        for (int u = 0; u < 4; ++u)
            *reinterpret_cast<v8s*>(&SBm[t * 32 + u * 8]) =
                *reinterpret_cast<const v8s*>(&srcB[t * 32 + u * 8]);
    }
    bf16x8 cur[8], nxt[8];
    {
        const unsigned short* ga = PA + (size_t)(b * 16 + 1) * 8192;
#pragma unroll
        for (int qv = 0; qv < 8; ++qv)
            cur[qv] = *reinterpret_cast<const bf16x8*>(&ga[aoff[qv]]);
    }
    __syncthreads();

#pragma unroll 1
    for (int j = 1; j < 15; ++j) {
        const unsigned short* ga = PA + (size_t)(b * 16 + j + 1) * 8192;
#pragma unroll
        for (int qv = 0; qv < 8; ++qv)
            nxt[qv] = *reinterpret_cast<const bf16x8*>(&ga[aoff[qv]]);

        v16f acc;
#pragma unroll
        for (int z = 0; z < 16; ++z) acc[z] = 0.f;
#pragma unroll
        for (int s4 = 0; s4 < 4; ++s4) {
            bf16x8 bh = *reinterpret_cast<const bf16x8*>(&SBm[boff[s4]]);
            bf16x8 bl = *reinterpret_cast<const bf16x8*>(&SBm[4096 + boff[s4]]);
            acc = __builtin_amdgcn_mfma_f32_32x32x16_bf16(cur[s4 + 4], bh, acc, 0, 0, 0);
            acc = __builtin_amdgcn_mfma_f32_32x32x16_bf16(cur[s4], bl, acc, 0, 0, 0);
            acc = __builtin_amdgcn_mfma_f32_32x32x16_bf16(cur[s4], bh, acc, 0, 0, 0);
        }
        __syncthreads();
#pragma unroll
        for (int rg = 0; rg < 4; ++rg) {
            float f[4];
#pragma unroll
            for (int r = 0; r < 4; ++r) f[r] = acc[4 * rg + r];
            v4s hi4, lo4;
            split4(f, hi4, lo4);
            *reinterpret_cast<v4s*>(&SBm[doff[rg]]) = hi4;
            *reinterpret_cast<v4s*>(&SBm[4096 + doff[rg]]) = lo4;
        }
        __syncthreads();
#pragma unroll
        for (int qv = 0; qv < 8; ++qv) cur[qv] = nxt[qv];
    }

    // final step (j = 15): write result to Sf as f32
    {
        v16f acc;
#pragma unroll
        for (int z = 0; z < 16; ++z) acc[z] = 0.f;
#pragma unroll
        for (int s4 = 0; s4 < 4; ++s4) {
            bf16x8 bh = *reinterpret_cast<const bf16x8*>(&SBm[boff[s4]]);
            bf16x8 bl = *reinterpret_cast<const bf16x8*>(&SBm[4096 + boff[s4]]);
            acc = __builtin_amdgcn_mfma_f32_32x32x16_bf16(cur[s4 + 4], bh, acc, 0, 0, 0);
            acc = __builtin_amdgcn_mfma_f32_32x32x16_bf16(cur[s4], bl, acc, 0, 0, 0);
            acc = __builtin_amdgcn_mfma_f32_32x32x16_bf16(cur[s4], bh, acc, 0, 0, 0);
        }
#pragma unroll
        for (int rg = 0; rg < 4; ++rg)
#pragma unroll
            for (int r = 0; r < 4; ++r)
                Sf[(32 * rw + 8 * rg + 4 * h + r) * 68 + n] = acc[4 * rg + r];
    }
    __syncthreads();

    // readout: h = relu(vec(S) @ W1 + b1); logits = h @ W2 + b2
    const int jg = t & 15, qd = t >> 4, j4 = jg << 2;
    float hp[4] = {0.f, 0.f, 0.f, 0.f};
#pragma unroll 4
    for (int mm = 0; mm < 256; ++mm) {
        const int nn = (qd << 8) + mm;
        const float vn = Sf[(nn >> 6) * 68 + (nn & 63)];
        const float4 wv = *reinterpret_cast<const float4*>(&W1[nn * 64 + j4]);
        hp[0] += vn * wv.x; hp[1] += vn * wv.y; hp[2] += vn * wv.z; hp[3] += vn * wv.w;
    }
    float* hpart = reinterpret_cast<float*>(SBm);   // SBm no longer needed
    *reinterpret_cast<float4*>(&hpart[qd * 64 + j4]) = make_float4(hp[0], hp[1], hp[2], hp[3]);
    __syncthreads();
    if (t < 64) {
        float hh = b1[t];
#pragma unroll
        for (int q2 = 0; q2 < 16; ++q2) hh += hpart[q2 * 64 + t];
        hl[t] = fmaxf(hh, 0.f);
    }
    __syncthreads();
    if (t < 60) {
        float a2 = b2[t];
#pragma unroll
        for (int jj = 0; jj < 64; ++jj) a2 += hl[jj] * W2[jj * 60 + t];
        out[b * 60 + t] = a2;
    }
}

// ---------------- launch ----------------
extern "C" void kernel_launch(void* const* d_in, const int* in_sizes, int n_in,
                              void* d_out, int out_size, void* d_ws, size_t ws_size,
                              hipStream_t stream) {
    (void)in_sizes; (void)n_in; (void)out_size; (void)ws_size;
    const int*   ids  = (const int*)d_in[0];
    const float* repr = (const float*)d_in[1];
    const float* W1   = (const float*)d_in[2];
    const float* b1   = (const float*)d_in[3];
    const float* W2   = (const float*)d_in[4];
    const float* b2   = (const float*)d_in[5];
    float* out = (float*)d_out;

    char* ws = (char*)d_ws;
    unsigned short* qtabA = (unsigned short*)(ws);                   // 60*16KB  < 1MB
    unsigned short* qtabB = (unsigned short*)(ws + (1u << 20));      // 60*16KB  < 1MB
    unsigned short* PA    = (unsigned short*)(ws + (2u << 20));      // 512*16KB = 8MB
    unsigned short* PB    = (unsigned short*)(ws + (10u << 20));     // 32*16KB  = 512KB

    qr_kernel<<<60, 64, 0, stream>>>(repr, qtabA, qtabB);
    scan1_kernel<<<512, 256, 0, stream>>>(ids, qtabA, qtabB, PA, PB);
    scan2_kernel<<<32, 256, 0, stream>>>(PA, PB, W1, b1, W2, b2, out);
}

// Round 8
// 222.719 us; speedup vs baseline: 1.1966x; 1.1966x over previous
//
#include <hip/hip_runtime.h>

// B=32, T=512, D=64, V=60
// inputs: [0] input_ids int32 [32*512], [1] repr_tab f32 [60*64*64],
//         [2] W1 f32 [4096*64], [3] b1 f32 [64], [4] W2 f32 [64*60], [5] b2 f32 [60]
// output: logits f32 [32*60]
//
// Pipeline:
//   qr_kernel    (60 blocks):  ROUND-4-VALIDATED Householder QR math (LAPACK
//                              convention, exact masked tail-sigma — NO total-al^2
//                              cancellation, see rounds 5/6 post-mortem). ONLY change
//                              vs round 7: column broadcast via LDS publish+readback
//                              (16 ds_write_b128 + 16 broadcast ds_read_b128 + 1
//                              scalar read for al) instead of 64 ds_bpermute + a
//                              64-deep cndmask chain.
//   scan1_kernel (512 blocks): chains of 32 Q-factors; S in LDS (bf16 hi/lo, B-layout);
//                              A-fragments direct global->reg, prefetched; 3-term
//                              split-bf16 MFMA (32x32x16) via compiler builtin.
//   scan2_kernel (32 blocks):  product of 16 chunk-products per batch + fused readout.
//
// Layout glossary (all bf16 planes are 4096 shorts; hi plane at +0, lo at +4096):
//   granule(row r, G=k>>3) at short offset r*64 + ((G ^ (r&7) ^ (r>>3)) << 3) + (k&7)
//   A-plane: r indexes the MFMA A operand rows, k its K-dim (8 consecutive)
//   B-plane: r indexes the MFMA B operand cols, k its K-dim (8 consecutive)
//   Empirically validated mapping (rounds 2/4/7): forward-fused q -> A-plane direct;
//   LDS-transposed q -> B-plane.

typedef short v8s __attribute__((ext_vector_type(8)));
typedef short v4s __attribute__((ext_vector_type(4)));
typedef float v16f __attribute__((ext_vector_type(16)));
typedef __bf16 bf16x8 __attribute__((ext_vector_type(8)));

// f32 -> (hi, lo) bf16 with RNE, branch-free bit tricks.
__device__ __forceinline__ void split_one(float f, unsigned& hi, unsigned& lo) {
    unsigned u = __float_as_uint(f);
    unsigned rh = u + 0x7fffu + ((u >> 16) & 1u);
    float fh = __uint_as_float(rh & 0xffff0000u);
    hi = rh >> 16;
    float g = f - fh;                     // exact (Sterbenz)
    unsigned ul = __float_as_uint(g);
    unsigned rl = ul + 0x7fffu + ((ul >> 16) & 1u);
    lo = rl >> 16;
}

__device__ __forceinline__ void split4(const float* f, v4s& hi4, v4s& lo4) {
#pragma unroll
    for (int r = 0; r < 4; ++r) {
        unsigned h, l;
        split_one(f[r], h, l);
        hi4[r] = (short)h;
        lo4[r] = (short)l;
    }
}

__device__ __forceinline__ void split8(const float* f, v8s& hi8, v8s& lo8) {
#pragma unroll
    for (int r = 0; r < 8; ++r) {
        unsigned h, l;
        split_one(f[r], h, l);
        hi8[r] = (short)h;
        lo8[r] = (short)l;
    }
}

// ---------------- Kernel 1: one-wave Householder QR, LDS column broadcast ----------------
// ROUND-4 math. Lane l holds column l of A and forward-fused Q-row accumulator q.
// LAPACK sgeqr2 convention: beta = -sign(alpha)*norm, tau=(beta-alpha)/beta,
// v_i = x_i/(alpha-beta), v_k=1. Q accumulated forward: q <- q - tau*(q.v)*v.
// Broadcast of column k: lane k publishes raw column to LDS; all lanes read back.
// Masking/sigma applied on readback values (exact tail-sum -> no cancellation).
__global__ __launch_bounds__(64, 1) void qr_kernel(const float* __restrict__ repr,
                                                   unsigned short* __restrict__ qtabA,
                                                   unsigned short* __restrict__ qtabB) {
    __shared__ float col[68];     // published raw column
    const int l = threadIdx.x;
    const int v = blockIdx.x;
    const float* src = repr + v * 4096;

    float a[64];   // column l of A
    float q[64];   // forward-fused Q accumulator (row l)
#pragma unroll
    for (int i = 0; i < 64; ++i) a[i] = src[i * 64 + l];
#pragma unroll
    for (int i = 0; i < 64; ++i) q[i] = (i == l) ? 1.f : 0.f;

#pragma unroll 1
    for (int k = 0; k < 64; ++k) {
        // lane k publishes its raw column (single wave: DS ops are in program order)
        if (l == k) {
#pragma unroll
            for (int c = 0; c < 16; ++c)
                *reinterpret_cast<float4*>(&col[4 * c]) =
                    make_float4(a[4 * c], a[4 * c + 1], a[4 * c + 2], a[4 * c + 3]);
        }
        __builtin_amdgcn_sched_barrier(0);   // forbid hoisting reads above masked writes

        // all lanes read the column back (broadcast reads, conflict-free)
        float vr[64];
#pragma unroll
        for (int c = 0; c < 16; ++c) {
            float4 x = *reinterpret_cast<const float4*>(&col[4 * c]);
            vr[4 * c] = x.x; vr[4 * c + 1] = x.y; vr[4 * c + 2] = x.z; vr[4 * c + 3] = x.w;
        }
        const float al = col[k];   // scalar broadcast read (replaces 64-cndmask chain)

        // sigma = exact masked tail-sum (round-4 formulation; immune to cancellation)
        float s0 = 0.f, s1 = 0.f, s2 = 0.f, s3 = 0.f;
#pragma unroll
        for (int i = 0; i < 64; i += 4) {
            s0 += (i     > k) ? vr[i]     * vr[i]     : 0.f;
            s1 += (i + 1 > k) ? vr[i + 1] * vr[i + 1] : 0.f;
            s2 += (i + 2 > k) ? vr[i + 2] * vr[i + 2] : 0.f;
            s3 += (i + 3 > k) ? vr[i + 3] * vr[i + 3] : 0.f;
        }
        const float sigma = (s0 + s1) + (s2 + s3);

        float beta, tau, scl;
        if (sigma == 0.f) { beta = al; tau = 0.f; scl = 0.f; }
        else {
            beta = -copysignf(sqrtf(al * al + sigma), al);
            tau = (beta - al) / beta;
            scl = 1.f / (al - beta);
        }

        // finalize v: 0 below k, 1 at k, scaled above k (round-4 verbatim)
#pragma unroll
        for (int i = 0; i < 64; ++i) vr[i] = (i < k) ? 0.f : ((i == k) ? 1.f : vr[i] * scl);

        // trailing update of own column: a -= tau*(v^T a) * v
        float w0 = 0.f, w1 = 0.f, w2 = 0.f, w3 = 0.f;
#pragma unroll
        for (int i = 0; i < 64; i += 4) {
            w0 += vr[i] * a[i]; w1 += vr[i + 1] * a[i + 1];
            w2 += vr[i + 2] * a[i + 2]; w3 += vr[i + 3] * a[i + 3];
        }
        const float tw = tau * ((w0 + w1) + (w2 + w3));
#pragma unroll
        for (int i = 0; i < 64; ++i) a[i] -= tw * vr[i];

        // forward Q accumulation on own row: q -= tau*(q . v) * v
        float u0 = 0.f, u1 = 0.f, u2 = 0.f, u3 = 0.f;
#pragma unroll
        for (int j = 0; j < 64; j += 4) {
            u0 += q[j] * vr[j]; u1 += q[j + 1] * vr[j + 1];
            u2 += q[j + 2] * vr[j + 2]; u3 += q[j + 3] * vr[j + 3];
        }
        const float tu = tau * ((u0 + u1) + (u2 + u3));
#pragma unroll
        for (int j = 0; j < 64; ++j) q[j] -= tu * vr[j];

        __builtin_amdgcn_sched_barrier(0);   // next iter's publish stays below our reads
    }

    // ---- A-plane DIRECT from q (round-2/4/7 validated mapping) ----
    {
        unsigned short* dstA = qtabA + (size_t)v * 8192 + (size_t)l * 64;
#pragma unroll
        for (int G = 0; G < 8; ++G) {
            v8s hi8, lo8;
            split8(&q[8 * G], hi8, lo8);
            const int sl = (G ^ (l & 7) ^ (l >> 3)) << 3;
            *reinterpret_cast<v8s*>(&dstA[sl]) = hi8;
            *reinterpret_cast<v8s*>(&dstA[4096 + sl]) = lo8;
        }
    }
    // ---- transpose through LDS, then B-plane (round-2/4/7 validated mapping) ----
    __shared__ float tr[64 * 65];
#pragma unroll
    for (int j = 0; j < 64; ++j) tr[l * 65 + j] = q[j];
    __syncthreads();
    {
        unsigned short* dstB = qtabB + (size_t)v * 8192 + (size_t)l * 64;
#pragma unroll
        for (int G = 0; G < 8; ++G) {
            float cv[8];
#pragma unroll
            for (int i = 0; i < 8; ++i) cv[i] = tr[(8 * G + i) * 65 + l];
            v8s hi8, lo8;
            split8(cv, hi8, lo8);
            const int sl = (G ^ (l & 7) ^ (l >> 3)) << 3;
            *reinterpret_cast<v8s*>(&dstB[sl]) = hi8;
            *reinterpret_cast<v8s*>(&dstB[4096 + sl]) = lo8;
        }
    }
}

// ---------------- Kernel 2: chains of 32 factors, 4 waves, MFMA ----------------
__global__ __launch_bounds__(256) void scan1_kernel(const int* __restrict__ ids,
                                                    const unsigned short* __restrict__ qtabA,
                                                    const unsigned short* __restrict__ qtabB,
                                                    unsigned short* __restrict__ PA,
                                                    unsigned short* __restrict__ PB) {
    __shared__ unsigned short SBm[8192];   // hi plane [0,4096), lo plane [4096,8192)
    __shared__ int ids_s[32];
    const int t = threadIdx.x;
    const int l = t & 63, w = t >> 6;
    const int rw = w >> 1, cw = w & 1, h = l >> 5;
    const int b = blockIdx.x >> 4, c = blockIdx.x & 15;
    if (t < 32) ids_s[t] = ids[b * 512 + c * 32 + t];

    const int m = 32 * rw + (l & 31);   // A-operand row
    const int n = 32 * cw + (l & 31);   // B-operand / D col
    int aoff[8], boff[4], doff[4];
#pragma unroll
    for (int s4 = 0; s4 < 4; ++s4) {
        const int G = 2 * s4 + h;
        aoff[s4]     = m * 64 + ((G ^ (m & 7) ^ (m >> 3)) << 3);
        aoff[s4 + 4] = aoff[s4] + 4096;
        boff[s4]     = n * 64 + ((G ^ (n & 7) ^ (n >> 3)) << 3);
    }
#pragma unroll
    for (int rg = 0; rg < 4; ++rg)
        doff[rg] = n * 64 + (((4 * rw + rg) ^ (n & 7) ^ (n >> 3)) << 3) + 4 * h;

    __syncthreads();   // ids_s visible

    // stage S = Q[ids[0]] (B-layout, linear copy)
    {
        const unsigned short* srcB = qtabB + (size_t)ids_s[0] * 8192;
#pragma unroll
        for (int u = 0; u < 4; ++u)
            *reinterpret_cast<v8s*>(&SBm[t * 32 + u * 8]) =
                *reinterpret_cast<const v8s*>(&srcB[t * 32 + u * 8]);
    }
    // prefetch A-fragments for factor 1
    bf16x8 cur[8], nxt[8];
    {
        const unsigned short* ga = qtabA + (size_t)ids_s[1] * 8192;
#pragma unroll
        for (int qv = 0; qv < 8; ++qv)
            cur[qv] = *reinterpret_cast<const bf16x8*>(&ga[aoff[qv]]);
    }
    __syncthreads();   // SBm staged

#pragma unroll 1
    for (int j = 1; j < 32; ++j) {
        const int vn = ids_s[(j < 31) ? (j + 1) : 31];
        const unsigned short* ga = qtabA + (size_t)vn * 8192;
#pragma unroll
        for (int qv = 0; qv < 8; ++qv)
            nxt[qv] = *reinterpret_cast<const bf16x8*>(&ga[aoff[qv]]);

        v16f acc;
#pragma unroll
        for (int z = 0; z < 16; ++z) acc[z] = 0.f;

#pragma unroll
        for (int s4 = 0; s4 < 4; ++s4) {
            bf16x8 bh = *reinterpret_cast<const bf16x8*>(&SBm[boff[s4]]);
            bf16x8 bl = *reinterpret_cast<const bf16x8*>(&SBm[4096 + boff[s4]]);
            acc = __builtin_amdgcn_mfma_f32_32x32x16_bf16(cur[s4 + 4], bh, acc, 0, 0, 0); // lo*hi
            acc = __builtin_amdgcn_mfma_f32_32x32x16_bf16(cur[s4], bl, acc, 0, 0, 0);     // hi*lo
            acc = __builtin_amdgcn_mfma_f32_32x32x16_bf16(cur[s4], bh, acc, 0, 0, 0);     // hi*hi
        }
        __syncthreads();   // all B-reads done before S is overwritten
#pragma unroll
        for (int rg = 0; rg < 4; ++rg) {
            float f[4];
#pragma unroll
            for (int r = 0; r < 4; ++r) f[r] = acc[4 * rg + r];
            v4s hi4, lo4;
            split4(f, hi4, lo4);
            *reinterpret_cast<v4s*>(&SBm[doff[rg]]) = hi4;
            *reinterpret_cast<v4s*>(&SBm[4096 + doff[rg]]) = lo4;
        }
        __syncthreads();   // new S visible
#pragma unroll
        for (int qv = 0; qv < 8; ++qv) cur[qv] = nxt[qv];
    }

    if (c == 0) {
        // B-layout copy (linear) for scan2's initial state
        unsigned short* dst = PB + (size_t)b * 8192;
#pragma unroll
        for (int u = 0; u < 4; ++u)
            *reinterpret_cast<v8s*>(&dst[t * 32 + u * 8]) =
                *reinterpret_cast<const v8s*>(&SBm[t * 32 + u * 8]);
    } else {
        // gather-transpose SBm (B-layout) -> A-layout global
        unsigned short* dst = PA + (size_t)(b * 16 + c) * 8192;
        const int mm = t & 63;
#pragma unroll
        for (int u = 0; u < 4; ++u) {
            const int p = u & 1;
            const int G = 2 * (t >> 6) + (u >> 1);
            v8s pk;
#pragma unroll
            for (int i = 0; i < 8; ++i)
                pk[i] = (short)SBm[p * 4096 + (8 * G + i) * 64 +
                                   (((mm >> 3) ^ i ^ G) << 3) + (mm & 7)];
            *reinterpret_cast<v8s*>(
                &dst[p * 4096 + mm * 64 + ((G ^ (mm & 7) ^ (mm >> 3)) << 3)]) = pk;
        }
    }
}

// ---------------- Kernel 3: per-batch product of 16 chunks + readout ----------------
__global__ __launch_bounds__(256) void scan2_kernel(const unsigned short* __restrict__ PA,
                                                    const unsigned short* __restrict__ PB,
                                                    const float* __restrict__ W1,
                                                    const float* __restrict__ b1,
                                                    const float* __restrict__ W2,
                                                    const float* __restrict__ b2,
                                                    float* __restrict__ out) {
    __shared__ unsigned short SBm[8192];
    __shared__ float Sf[64 * 68];
    __shared__ float hl[64];
    const int t = threadIdx.x;
    const int l = t & 63, w = t >> 6;
    const int rw = w >> 1, cw = w & 1, h = l >> 5;
    const int b = blockIdx.x;

    const int m = 32 * rw + (l & 31);
    const int n = 32 * cw + (l & 31);
    int aoff[8], boff[4], doff[4];
#pragma unroll
    for (int s4 = 0; s4 < 4; ++s4) {
        const int G = 2 * s4 + h;
        aoff[s4]     = m * 64 + ((G ^ (m & 7) ^ (m >> 3)) << 3);
        aoff[s4 + 4] = aoff[s4] + 4096;
        boff[s4]     = n * 64 + ((G ^ (n & 7) ^ (n >> 3)) << 3);
    }
#pragma unroll
    for (int rg = 0; rg < 4; ++rg)
        doff[rg] = n * 64 + (((4 * rw + rg) ^ (n & 7) ^ (n >> 3)) << 3) + 4 * h;

    // stage S = chunk(b*16 + 0) from PB
    {
        const unsigned short* srcB = PB + (size_t)b * 8192;
#pragma unroll
        for (int u = 0; u < 4; ++u)
            *reinterpret_cast<v8s*>(&SBm[t * 32 + u * 8]) =
                *reinterpret_cast<const v8s*>(&srcB[t * 32 + u * 8]);
    }
    bf16x8 cur[8], nxt[8];
    {
        const unsigned short* ga = PA + (size_t)(b * 16 + 1) * 8192;
#pragma unroll
        for (int qv = 0; qv < 8; ++qv)
            cur[qv] = *reinterpret_cast<const bf16x8*>(&ga[aoff[qv]]);
    }
    __syncthreads();

#pragma unroll 1
    for (int j = 1; j < 15; ++j) {
        const unsigned short* ga = PA + (size_t)(b * 16 + j + 1) * 8192;
#pragma unroll
        for (int qv = 0; qv < 8; ++qv)
            nxt[qv] = *reinterpret_cast<const bf16x8*>(&ga[aoff[qv]]);

        v16f acc;
#pragma unroll
        for (int z = 0; z < 16; ++z) acc[z] = 0.f;
#pragma unroll
        for (int s4 = 0; s4 < 4; ++s4) {
            bf16x8 bh = *reinterpret_cast<const bf16x8*>(&SBm[boff[s4]]);
            bf16x8 bl = *reinterpret_cast<const bf16x8*>(&SBm[4096 + boff[s4]]);
            acc = __builtin_amdgcn_mfma_f32_32x32x16_bf16(cur[s4 + 4], bh, acc, 0, 0, 0);
            acc = __builtin_amdgcn_mfma_f32_32x32x16_bf16(cur[s4], bl, acc, 0, 0, 0);
            acc = __builtin_amdgcn_mfma_f32_32x32x16_bf16(cur[s4], bh, acc, 0, 0, 0);
        }
        __syncthreads();
#pragma unroll
        for (int rg = 0; rg < 4; ++rg) {
            float f[4];
#pragma unroll
            for (int r = 0; r < 4; ++r) f[r] = acc[4 * rg + r];
            v4s hi4, lo4;
            split4(f, hi4, lo4);
            *reinterpret_cast<v4s*>(&SBm[doff[rg]]) = hi4;
            *reinterpret_cast<v4s*>(&SBm[4096 + doff[rg]]) = lo4;
        }
        __syncthreads();
#pragma unroll
        for (int qv = 0; qv < 8; ++qv) cur[qv] = nxt[qv];
    }

    // final step (j = 15): write result to Sf as f32
    {
        v16f acc;
#pragma unroll
        for (int z = 0; z < 16; ++z) acc[z] = 0.f;
#pragma unroll
        for (int s4 = 0; s4 < 4; ++s4) {
            bf16x8 bh = *reinterpret_cast<const bf16x8*>(&SBm[boff[s4]]);
            bf16x8 bl = *reinterpret_cast<const bf16x8*>(&SBm[4096 + boff[s4]]);
            acc = __builtin_amdgcn_mfma_f32_32x32x16_bf16(cur[s4 + 4], bh, acc, 0, 0, 0);
            acc = __builtin_amdgcn_mfma_f32_32x32x16_bf16(cur[s4], bl, acc, 0, 0, 0);
            acc = __builtin_amdgcn_mfma_f32_32x32x16_bf16(cur[s4], bh, acc, 0, 0, 0);
        }
#pragma unroll
        for (int rg = 0; rg < 4; ++rg)
#pragma unroll
            for (int r = 0; r < 4; ++r)
                Sf[(32 * rw + 8 * rg + 4 * h + r) * 68 + n] = acc[4 * rg + r];
    }
    __syncthreads();

    // readout: h = relu(vec(S) @ W1 + b1); logits = h @ W2 + b2
    const int jg = t & 15, qd = t >> 4, j4 = jg << 2;
    float hp[4] = {0.f, 0.f, 0.f, 0.f};
#pragma unroll 4
    for (int mm = 0; mm < 256; ++mm) {
        const int nn = (qd << 8) + mm;
        const float vn = Sf[(nn >> 6) * 68 + (nn & 63)];
        const float4 wv = *reinterpret_cast<const float4*>(&W1[nn * 64 + j4]);
        hp[0] += vn * wv.x; hp[1] += vn * wv.y; hp[2] += vn * wv.z; hp[3] += vn * wv.w;
    }
    float* hpart = reinterpret_cast<float*>(SBm);   // SBm no longer needed
    *reinterpret_cast<float4*>(&hpart[qd * 64 + j4]) = make_float4(hp[0], hp[1], hp[2], hp[3]);
    __syncthreads();
    if (t < 64) {
        float hh = b1[t];
#pragma unroll
        for (int q2 = 0; q2 < 16; ++q2) hh += hpart[q2 * 64 + t];
        hl[t] = fmaxf(hh, 0.f);
    }
    __syncthreads();
    if (t < 60) {
        float a2 = b2[t];
#pragma unroll
        for (int jj = 0; jj < 64; ++jj) a2 += hl[jj] * W2[jj * 60 + t];
        out[b * 60 + t] = a2;
    }
}

// ---------------- launch ----------------
extern "C" void kernel_launch(void* const* d_in, const int* in_sizes, int n_in,
                              void* d_out, int out_size, void* d_ws, size_t ws_size,
                              hipStream_t stream) {
    (void)in_sizes; (void)n_in; (void)out_size; (void)ws_size;
    const int*   ids  = (const int*)d_in[0];
    const float* repr = (const float*)d_in[1];
    const float* W1   = (const float*)d_in[2];
    const float* b1   = (const float*)d_in[3];
    const float* W2   = (const float*)d_in[4];
    const float* b2   = (const float*)d_in[5];
    float* out = (float*)d_out;

    char* ws = (char*)d_ws;
    unsigned short* qtabA = (unsigned short*)(ws);                   // 60*16KB  < 1MB
    unsigned short* qtabB = (unsigned short*)(ws + (1u << 20));      // 60*16KB  < 1MB
    unsigned short* PA    = (unsigned short*)(ws + (2u << 20));      // 512*16KB = 8MB
    unsigned short* PB    = (unsigned short*)(ws + (10u << 20));     // 32*16KB  = 512KB

    qr_kernel<<<60, 64, 0, stream>>>(repr, qtabA, qtabB);
    scan1_kernel<<<512, 256, 0, stream>>>(ids, qtabA, qtabB, PA, PB);
    scan2_kernel<<<32, 256, 0, stream>>>(PA, PB, W1, b1, W2, b2, out);
}